// Round 3
// baseline (3507.565 us; speedup 1.0000x reference)
//
#include <hip/hip_runtime.h>

#define CDIV(a,b) (((a)+(b)-1)/(b))

typedef __bf16 bf16x8 __attribute__((ext_vector_type(8)));
typedef float  f32x4  __attribute__((ext_vector_type(4)));
#define MFMA16(a,b,c) __builtin_amdgcn_mfma_f32_16x16x32_bf16(a,b,c,0,0,0)

// ---------------- wave/block reductions ----------------
__device__ __forceinline__ float waveSum(float v){
#pragma unroll
  for(int o=32;o;o>>=1) v += __shfl_xor(v,o);
  return v;
}
__device__ __forceinline__ float waveMax(float v){
#pragma unroll
  for(int o=32;o;o>>=1) v = fmaxf(v,__shfl_xor(v,o));
  return v;
}

// ---------------- bf16 split helpers ----------------
__device__ __forceinline__ unsigned short f2bf(float f){
  unsigned u = __float_as_uint(f);
  u += 0x7FFFu + ((u>>16)&1u);
  return (unsigned short)(u>>16);
}
__device__ __forceinline__ float bf2f(unsigned short h){
  return __uint_as_float(((unsigned)h)<<16);
}
__device__ __forceinline__ void pack8(const float4& x, const float4& y,
                                      uint4& hi, uint4& lo){
  float v[8] = {x.x,x.y,x.z,x.w,y.x,y.y,y.z,y.w};
  unsigned short h[8], l[8];
#pragma unroll
  for(int i=0;i<8;i++){
    h[i] = f2bf(v[i]);
    l[i] = f2bf(v[i] - bf2f(h[i]));
  }
  hi = make_uint4((unsigned)h[0]|((unsigned)h[1]<<16), (unsigned)h[2]|((unsigned)h[3]<<16),
                  (unsigned)h[4]|((unsigned)h[5]<<16), (unsigned)h[6]|((unsigned)h[7]<<16));
  lo = make_uint4((unsigned)l[0]|((unsigned)l[1]<<16), (unsigned)l[2]|((unsigned)l[3]<<16),
                  (unsigned)l[4]|((unsigned)l[5]<<16), (unsigned)l[6]|((unsigned)l[7]<<16));
}

__device__ __forceinline__ bf16x8 ldsfrag(const unsigned short* base, int row, int kb){
  int off = (row<<7) + (kb<<1);
  off ^= (row&7)<<4;
  return *reinterpret_cast<const bf16x8*>(reinterpret_cast<const char*>(base) + off);
}

// ---------------- MFMA bf16x3 NT GEMM, f32 W (setup paths) ----------------
template<int ACT>
__global__ __launch_bounds__(256)
void gemm3(const float* __restrict__ A, int lda,
           const float* __restrict__ W, int ldw,
           float* __restrict__ C, int ldc,
           const float* __restrict__ bias, int M, int N, int K, float scale)
{
  __shared__ unsigned short AsH[64*64];
  __shared__ unsigned short AsL[64*64];
  __shared__ unsigned short WsH[64*64];
  __shared__ unsigned short WsL[64*64];
  const int tid  = threadIdx.x;
  const int bm   = blockIdx.x*64, bn = blockIdx.y*64;
  const int lane = tid & 63, wid = tid >> 6;
  const int wm   = (wid&1)*32, wn = (wid>>1)*32;
  const int r0   = tid>>3;
  const int kq   = (tid&7)*8;

  float4 gA[2][2], gW[2][2];
  auto loadG = [&](int k0){
#pragma unroll
    for(int i=0;i<2;i++){
      int r = r0 + i*32;
      if(bm+r < M){
        const float* pa = A + (size_t)(bm+r)*lda + k0 + kq;
        gA[i][0] = *reinterpret_cast<const float4*>(pa);
        gA[i][1] = *reinterpret_cast<const float4*>(pa+4);
      } else {
        gA[i][0] = make_float4(0.f,0.f,0.f,0.f);
        gA[i][1] = make_float4(0.f,0.f,0.f,0.f);
      }
      const float* pw = W + (size_t)(bn+r)*ldw + k0 + kq;
      gW[i][0] = *reinterpret_cast<const float4*>(pw);
      gW[i][1] = *reinterpret_cast<const float4*>(pw+4);
    }
  };
  auto writeL = [&](){
#pragma unroll
    for(int i=0;i<2;i++){
      int r = r0 + i*32;
      int off = (r<<7) + (tid&7)*16;
      off ^= (r&7)<<4;
      uint4 hi, lo;
      pack8(gA[i][0], gA[i][1], hi, lo);
      *reinterpret_cast<uint4*>(reinterpret_cast<char*>(AsH) + off) = hi;
      *reinterpret_cast<uint4*>(reinterpret_cast<char*>(AsL) + off) = lo;
      pack8(gW[i][0], gW[i][1], hi, lo);
      *reinterpret_cast<uint4*>(reinterpret_cast<char*>(WsH) + off) = hi;
      *reinterpret_cast<uint4*>(reinterpret_cast<char*>(WsL) + off) = lo;
    }
  };

  f32x4 acc[2][2];
#pragma unroll
  for(int mi=0;mi<2;mi++)
#pragma unroll
    for(int ni=0;ni<2;ni++) acc[mi][ni] = f32x4{0.f,0.f,0.f,0.f};

  loadG(0);
  for(int k0=0; k0<K; k0+=64){
    __syncthreads();
    writeL();
    __syncthreads();
    if(k0+64 < K) loadG(k0+64);
    const int lk = (lane>>4)*8;
    const int lc = lane&15;
#pragma unroll
    for(int kk=0; kk<2; kk++){
      int kb = kk*32 + lk;
      bf16x8 aH[2], aL[2], bH[2], bL[2];
#pragma unroll
      for(int m=0;m<2;m++){
        aH[m] = ldsfrag(AsH, wm + lc + m*16, kb);
        aL[m] = ldsfrag(AsL, wm + lc + m*16, kb);
        bH[m] = ldsfrag(WsH, wn + lc + m*16, kb);
        bL[m] = ldsfrag(WsL, wn + lc + m*16, kb);
      }
#pragma unroll
      for(int mi=0;mi<2;mi++)
#pragma unroll
        for(int ni=0;ni<2;ni++){
          acc[mi][ni] = MFMA16(aH[mi], bH[ni], acc[mi][ni]);
          acc[mi][ni] = MFMA16(aH[mi], bL[ni], acc[mi][ni]);
          acc[mi][ni] = MFMA16(aL[mi], bH[ni], acc[mi][ni]);
        }
    }
  }

  const int lr = lane>>4, lc = lane&15;
#pragma unroll
  for(int mi=0;mi<2;mi++)
#pragma unroll
    for(int ni=0;ni<2;ni++)
#pragma unroll
      for(int r=0;r<4;r++){
        int row = bm + wm + mi*16 + lr*4 + r;
        if(row>=M) continue;
        int col = bn + wn + ni*16 + lc;
        float v = acc[mi][ni][r]*scale + (bias ? bias[col] : 0.f);
        if(ACT==1) v = 0.5f*v*(1.f+erff(v*0.70710678118654752f));
        C[(size_t)row*ldc+col] = v;
      }
}

// ---------------- MFMA bf16x3 NT GEMM, pre-split W (hot path) ----------------
template<int ACT>
__global__ __launch_bounds__(256)
void gemm3s(const float* __restrict__ A, int lda,
            const unsigned short* __restrict__ WH,
            const unsigned short* __restrict__ WL, int ldw,
            float* __restrict__ C, int ldc,
            const float* __restrict__ bias, int M, int N, int K)
{
  __shared__ unsigned short AsH[64*64];
  __shared__ unsigned short AsL[64*64];
  __shared__ unsigned short WsH[64*64];
  __shared__ unsigned short WsL[64*64];
  const int tid  = threadIdx.x;
  const int bm   = blockIdx.x*64, bn = blockIdx.y*64;
  const int lane = tid & 63, wid = tid >> 6;
  const int wm   = (wid&1)*32, wn = (wid>>1)*32;
  const int r0   = tid>>3;
  const int kq   = (tid&7)*8;

  float4 gA[2][2]; uint4 gWH[2], gWL[2];
  auto loadG = [&](int k0){
#pragma unroll
    for(int i=0;i<2;i++){
      int r = r0 + i*32;
      if(bm+r < M){
        const float* pa = A + (size_t)(bm+r)*lda + k0 + kq;
        gA[i][0] = *reinterpret_cast<const float4*>(pa);
        gA[i][1] = *reinterpret_cast<const float4*>(pa+4);
      } else {
        gA[i][0] = make_float4(0.f,0.f,0.f,0.f);
        gA[i][1] = make_float4(0.f,0.f,0.f,0.f);
      }
      gWH[i] = *reinterpret_cast<const uint4*>(WH + (size_t)(bn+r)*ldw + k0 + kq);
      gWL[i] = *reinterpret_cast<const uint4*>(WL + (size_t)(bn+r)*ldw + k0 + kq);
    }
  };
  auto writeL = [&](){
#pragma unroll
    for(int i=0;i<2;i++){
      int r = r0 + i*32;
      int off = (r<<7) + (tid&7)*16;
      off ^= (r&7)<<4;
      uint4 hi, lo;
      pack8(gA[i][0], gA[i][1], hi, lo);
      *reinterpret_cast<uint4*>(reinterpret_cast<char*>(AsH) + off) = hi;
      *reinterpret_cast<uint4*>(reinterpret_cast<char*>(AsL) + off) = lo;
      *reinterpret_cast<uint4*>(reinterpret_cast<char*>(WsH) + off) = gWH[i];
      *reinterpret_cast<uint4*>(reinterpret_cast<char*>(WsL) + off) = gWL[i];
    }
  };

  f32x4 acc[2][2];
#pragma unroll
  for(int mi=0;mi<2;mi++)
#pragma unroll
    for(int ni=0;ni<2;ni++) acc[mi][ni] = f32x4{0.f,0.f,0.f,0.f};

  loadG(0);
  for(int k0=0; k0<K; k0+=64){
    __syncthreads();
    writeL();
    __syncthreads();
    if(k0+64 < K) loadG(k0+64);
    const int lk = (lane>>4)*8;
    const int lc = lane&15;
#pragma unroll
    for(int kk=0; kk<2; kk++){
      int kb = kk*32 + lk;
      bf16x8 aH[2], aL[2], bH[2], bL[2];
#pragma unroll
      for(int m=0;m<2;m++){
        aH[m] = ldsfrag(AsH, wm + lc + m*16, kb);
        aL[m] = ldsfrag(AsL, wm + lc + m*16, kb);
        bH[m] = ldsfrag(WsH, wn + lc + m*16, kb);
        bL[m] = ldsfrag(WsL, wn + lc + m*16, kb);
      }
#pragma unroll
      for(int mi=0;mi<2;mi++)
#pragma unroll
        for(int ni=0;ni<2;ni++){
          acc[mi][ni] = MFMA16(aH[mi], bH[ni], acc[mi][ni]);
          acc[mi][ni] = MFMA16(aH[mi], bL[ni], acc[mi][ni]);
          acc[mi][ni] = MFMA16(aL[mi], bH[ni], acc[mi][ni]);
        }
    }
  }

  const int lr = lane>>4, lc = lane&15;
#pragma unroll
  for(int mi=0;mi<2;mi++)
#pragma unroll
    for(int ni=0;ni<2;ni++)
#pragma unroll
      for(int r=0;r<4;r++){
        int row = bm + wm + mi*16 + lr*4 + r;
        if(row>=M) continue;
        int col = bn + wn + ni*16 + lc;
        float v = acc[mi][ni][r] + (bias ? bias[col] : 0.f);
        if(ACT==1) v = 0.5f*v*(1.f+erff(v*0.70710678118654752f));
        C[(size_t)row*ldc+col] = v;
      }
}

// ---------------- f32 NN GEMM (setup compositions) ----------------
__global__ __launch_bounds__(256)
void gemm_nn(const float* __restrict__ A, int lda,
             const float* __restrict__ Bm, int ldb,
             float* __restrict__ C, int ldc,
             int M, int N, int K, float scale)
{
  __shared__ float As[16][68];
  __shared__ float Bs[16][68];
  const int bm = blockIdx.x*64, bn = blockIdx.y*64;
  const int tid = threadIdx.x;
  const int lr = tid>>2;
  const int kq = (tid&3)<<2;
  const int kr = tid>>4;
  const int nq = (tid&15)<<2;
  const int tx = tid&15, ty = tid>>4;
  float acc[4][4] = {};
  for(int k0=0;k0<K;k0+=16){
    float4 av = make_float4(0.f,0.f,0.f,0.f), bv = make_float4(0.f,0.f,0.f,0.f);
    if(bm+lr < M && k0+kq < K) av = *reinterpret_cast<const float4*>(A + (size_t)(bm+lr)*lda + k0+kq);
    if(k0+kr < K && bn+nq < N) bv = *reinterpret_cast<const float4*>(Bm + (size_t)(k0+kr)*ldb + bn+nq);
    As[kq+0][lr]=av.x; As[kq+1][lr]=av.y; As[kq+2][lr]=av.z; As[kq+3][lr]=av.w;
    Bs[kr][nq+0]=bv.x; Bs[kr][nq+1]=bv.y; Bs[kr][nq+2]=bv.z; Bs[kr][nq+3]=bv.w;
    __syncthreads();
#pragma unroll
    for(int k=0;k<16;k++){
      float4 a4 = *reinterpret_cast<const float4*>(&As[k][ty<<2]);
      float4 b4 = *reinterpret_cast<const float4*>(&Bs[k][tx<<2]);
      float aa[4]={a4.x,a4.y,a4.z,a4.w};
      float bb[4]={b4.x,b4.y,b4.z,b4.w};
#pragma unroll
      for(int i=0;i<4;i++)
#pragma unroll
        for(int j=0;j<4;j++) acc[i][j] = fmaf(aa[i],bb[j],acc[i][j]);
    }
    __syncthreads();
  }
#pragma unroll
  for(int i=0;i<4;i++){
    int row = bm + (ty<<2) + i;
    if(row>=M) continue;
#pragma unroll
    for(int j=0;j<4;j++){
      int col = bn + (tx<<2) + j;
      if(col>=N) continue;
      C[(size_t)row*ldc+col]=acc[i][j]*scale;
    }
  }
}

// ---------------- LayerNorm(x + t), row-per-block ----------------
__global__ __launch_bounds__(128)
void add_ln(const float* __restrict__ X, const float* __restrict__ T,
            float* __restrict__ O, const float* __restrict__ g,
            const float* __restrict__ be, int M)
{
  int row = blockIdx.x;
  if(row>=M) return;
  const float* x = X + (size_t)row*384;
  const float* t = T + (size_t)row*384;
  float* o = O + (size_t)row*384;
  int tid = threadIdx.x;
  float v[3]; float s=0.f;
#pragma unroll
  for(int i=0;i<3;i++){ int c = tid + i*128; v[i] = x[c] + t[c]; s += v[i]; }
  s = waveSum(s);
  __shared__ float p1[2];
  if((tid&63)==0) p1[tid>>6]=s;
  __syncthreads();
  float mean = (p1[0]+p1[1])*(1.f/384.f);
  float vs=0.f;
#pragma unroll
  for(int i=0;i<3;i++){ float d=v[i]-mean; vs += d*d; }
  vs = waveSum(vs);
  __shared__ float p2[2];
  if((tid&63)==0) p2[tid>>6]=vs;
  __syncthreads();
  float rstd = rsqrtf((p2[0]+p2[1])*(1.f/384.f) + 1e-5f);
#pragma unroll
  for(int i=0;i<3;i++){ int c = tid + i*128; o[c] = (v[i]-mean)*rstd*g[c] + be[c]; }
}

// ---------------- row softmax with ld + zero-pad tail ----------------
__global__ __launch_bounds__(256)
void softmax_rows(float* __restrict__ X, int ld, int cols)
{
  float* x = X + (size_t)blockIdx.x*ld;
  int tid = threadIdx.x;
  float m = -1e30f;
  for(int c=tid;c<cols;c+=256) m = fmaxf(m, x[c]);
  m = waveMax(m);
  __shared__ float sm[4];
  if((tid&63)==0) sm[tid>>6]=m;
  __syncthreads();
  m = fmaxf(fmaxf(sm[0],sm[1]),fmaxf(sm[2],sm[3]));
  float s=0.f;
  for(int c=tid;c<cols;c+=256){ float e = expf(x[c]-m); x[c]=e; s+=e; }
  s = waveSum(s);
  __shared__ float ss[4];
  if((tid&63)==0) ss[tid>>6]=s;
  __syncthreads();
  s = ss[0]+ss[1]+ss[2]+ss[3];
  float inv = 1.f/s;
  for(int c=tid;c<cols;c+=256) x[c]*=inv;
  for(int c=cols+tid;c<ld;c+=256) x[c]=0.f;
}

// ---------------- setup kernels ----------------
__global__ void prep_conv(const float* __restrict__ cw, const float* __restrict__ cb,
                          float* __restrict__ Wc, float* __restrict__ cb768){
  int gid = blockIdx.x*256+threadIdx.x;
  if(gid >= 384*384) return;
  int i = gid % 384, o = gid / 384;
  const float* w = cw + (size_t)gid*3;
  Wc[(size_t)o*768 + i]            = w[1];
  Wc[(size_t)o*768 + 384 + i]      = w[2];
  Wc[(size_t)(384+o)*768 + i]      = w[0];
  Wc[(size_t)(384+o)*768 + 384 + i]= w[1];
  if(gid < 768) cb768[gid] = cb[gid % 384];
}

__global__ void vt_k(const float* __restrict__ qkv, float* __restrict__ VT){
  int gid = blockIdx.x*256+threadIdx.x;
  if(gid >= 2*192*512) return;
  int k = gid & 511; int n = (gid>>9) % 192; int h = gid / 98304;
  VT[gid] = (k<500) ? qkv[(size_t)k*1152 + 768 + h*192 + n] : 0.f;
}

__global__ void compose_bias(const float* __restrict__ inw, const float* __restrict__ inb,
                             const float* __restrict__ qb, const float* __restrict__ kb,
                             const float* __restrict__ vb, float* __restrict__ cb){
  int gid = blockIdx.x*256+threadIdx.x;
  if(gid>=1536) return;
  int seg = gid/384, i = gid%384;
  const float* wrow; const float* bsrc; float b2;
  if(seg==0){ wrow=inw + (size_t)i*384;       bsrc=qb; b2=inb[i]; }
  else if(seg==1){ wrow=inw + (size_t)(384+i)*384; bsrc=kb; b2=inb[384+i]; }
  else if(seg==2){ wrow=inw + (size_t)(768+i)*384; bsrc=vb; b2=inb[768+i]; }
  else          { wrow=inw + (size_t)(768+i)*384; bsrc=kb; b2=inb[768+i]; }
  float s=0.f;
  for(int t=0;t<384;t++) s = fmaf(wrow[t], bsrc[t], s);
  cb[gid] = s + b2;
}

#define NSEG 16
struct SplitArgs {
  const float* src[NSEG];
  unsigned short* dh[NSEG];
  unsigned short* dl[NSEG];
  int start[NSEG+1];
};
__global__ void split_all(SplitArgs a){
  int gid = blockIdx.x*256+threadIdx.x;
  if(gid >= a.start[NSEG]) return;
  int s=0;
  while(s<NSEG-1 && gid >= a.start[s+1]) s++;
  int off = gid - a.start[s];
  float v = a.src[s][off];
  unsigned short h = f2bf(v);
  a.dh[s][off] = h;
  a.dl[s][off] = f2bf(v - bf2f(h));
}

__global__ void seq_init(const int* __restrict__ inp, const float* __restrict__ emb,
                         const float* __restrict__ rp, float* __restrict__ seq){
  int gid = blockIdx.x*256+threadIdx.x;
  if(gid >= 128*8*384) return;
  int j = gid % 384; int l = (gid/384) & 7; int b = gid / 3072;
  int tok = inp[b*8 + l];
  seq[gid] = emb[(size_t)tok*384 + j] + rp[l*384 + j];
}

// ---------------- merge-loop kernels ----------------
__global__ void build_pairs(const float* __restrict__ seq, const float* __restrict__ rp,
                            float* __restrict__ pairs, int N, int P){
  int gid = blockIdx.x*256+threadIdx.x;
  if(gid >= N*768) return;
  int c = gid % 768; int n = gid / 768;
  int t = c / 384; int j = c % 384;
  int i = n % P; int b = n / P;
  pairs[gid] = seq[((size_t)b*8 + i + t)*384 + j] + rp[t*384 + j];
}

// fused len-2 attention: one wave per (pair,t) row, 8 waves/block
__global__ __launch_bounds__(512)
void attn2_fused(const float* __restrict__ QKV, float* __restrict__ O, int rows){
  int w = threadIdx.x >> 6, lane = threadIdx.x & 63;
  int r = blockIdx.x*8 + w;
  if(r >= rows) return;
  const float* qr  = QKV + (size_t)r*1152;
  const float* kr0 = QKV + (size_t)(r & ~1)*1152 + 384;
  const float* vr0 = QKV + (size_t)(r & ~1)*1152 + 768;
  float* o = O + (size_t)r*384;
  const float sc = 0.1020620726159658f;   // 1/sqrt(96)
#pragma unroll
  for(int h=0;h<4;h++){
    const float* qp  = qr  + h*96;
    const float* k0p = kr0 + h*96;
    const float* k1p = k0p + 1152;
    const float* v0p = vr0 + h*96;
    const float* v1p = v0p + 1152;
    float qa = qp[lane];
    float s0 = qa*k0p[lane];
    float s1 = qa*k1p[lane];
    if(lane<32){
      float qb = qp[64+lane];
      s0 += qb*k0p[64+lane];
      s1 += qb*k1p[64+lane];
    }
    s0 = waveSum(s0)*sc; s1 = waveSum(s1)*sc;
    float mm = fmaxf(s0,s1);
    float e0 = expf(s0-mm), e1 = expf(s1-mm);
    float inv = 1.f/(e0+e1);
    e0*=inv; e1*=inv;
    o[h*96+lane] = e0*v0p[lane] + e1*v1p[lane];
    if(lane<32) o[h*96+64+lane] = e0*v0p[64+lane] + e1*v1p[64+lane];
  }
}

// fused score + argmax + entropy + gather; one block per batch
__global__ __launch_bounds__(256)
void score_select(const float* __restrict__ X, const float* __restrict__ w,
                  const float* __restrict__ b0, int P, int* __restrict__ idxb,
                  float* __restrict__ lossSlot, float* __restrict__ sel){
  int b = blockIdx.x;
  int tid = threadIdx.x, lane = tid&63, wv = tid>>6;
  __shared__ float scs[8];
  __shared__ int sidx;
  for(int pi=wv; pi<P; pi+=4){
    const float* x = X + (((size_t)b*P+pi)*2+1)*384;
    float s=0.f;
#pragma unroll
    for(int i=0;i<6;i++){ int c = lane + i*64; s = fmaf(x[c], w[c], s); }
    s = waveSum(s);
    if(lane==0) scs[pi] = 1.f/(1.f+expf(-(s + b0[0])));
  }
  __syncthreads();
  if(tid==0){
    float m = scs[0]; int am = 0;
    for(int i=1;i<P;i++){ float v=scs[i]; if(v>m){m=v;am=i;} }
    float z=0.f, sx=0.f;
    for(int i=0;i<P;i++){ float e=expf(scs[i]-m); z+=e; sx=fmaf(e,scs[i],sx); }
    lossSlot[(size_t)b*9] = (m + logf(z)) - sx/z;
    idxb[b] = am;
    sidx = am;
  }
  __syncthreads();
  const float* src = X + (((size_t)b*P+sidx)*2+1)*384;
  for(int c=tid;c<384;c+=256) sel[(size_t)b*384+c] = src[c];
}

// flash attention over 500 mem keys + 1 per-batch key
__global__ __launch_bounds__(256)
void flash_fuse(const float* __restrict__ fqkv1, const float* __restrict__ K1,
                const float* __restrict__ V1, float* __restrict__ O){
  int b = blockIdx.x/6, h = blockIdx.x%6;
  int tid = threadIdx.x, lane = tid&63, wv = tid>>6;
  __shared__ float pr[501];
  __shared__ float red[4][64];
  __shared__ float r4[4], r4b[4];
  const float* qp = fqkv1 + (size_t)b*1152 + h*64;
  float qd = qp[lane];
  for(int j=wv; j<501; j+=4){
    const float* kp = (j<500) ? K1 + (size_t)j*384 + h*64
                              : fqkv1 + (size_t)b*1152 + 384 + h*64;
    float s = waveSum(qd * kp[lane]) * 0.125f;
    if(lane==0) pr[j] = s;
  }
  __syncthreads();
  float m = -1e30f;
  for(int c=tid;c<501;c+=256) m = fmaxf(m, pr[c]);
  m = waveMax(m);
  if(lane==0) r4[wv]=m;
  __syncthreads();
  m = fmaxf(fmaxf(r4[0],r4[1]),fmaxf(r4[2],r4[3]));
  float s=0.f;
  for(int c=tid;c<501;c+=256){ float e=expf(pr[c]-m); pr[c]=e; s+=e; }
  s = waveSum(s);
  if(lane==0) r4b[wv]=s;
  __syncthreads();
  float inv = 1.f/(r4b[0]+r4b[1]+r4b[2]+r4b[3]);
  int d = tid&63, g = tid>>6;
  float acc=0.f;
  for(int j=g;j<501;j+=4){
    const float* vp = (j<500) ? V1 + (size_t)j*384
                              : fqkv1 + (size_t)b*1152 + 768;
    acc += pr[j]*vp[h*64+d];
  }
  red[g][d]=acc;
  __syncthreads();
  if(g==0) O[(size_t)b*384 + h*64 + d] = (red[0][d]+red[1][d]+red[2][d]+red[3][d])*inv;
}

// flash attention over 500 mem keys + 2 per-batch seq keys (final)
__global__ __launch_bounds__(256)
void flash_fin(const float* __restrict__ gqkv1, const float* __restrict__ K1,
               const float* __restrict__ V1, float* __restrict__ O){
  int bt = blockIdx.x/6, h = blockIdx.x%6;
  int b2 = bt & ~1;
  int tid = threadIdx.x, lane = tid&63, wv = tid>>6;
  __shared__ float pr[502];
  __shared__ float red[4][64];
  __shared__ float r4[4], r4b[4];
  const float* qp = gqkv1 + (size_t)bt*1152 + h*64;
  float qd = qp[lane];
  for(int j=wv; j<502; j+=4){
    const float* kp = (j<500) ? K1 + (size_t)j*384 + h*64
                              : gqkv1 + (size_t)(b2 + (j-500))*1152 + 384 + h*64;
    float s = waveSum(qd * kp[lane]) * 0.125f;
    if(lane==0) pr[j] = s;
  }
  __syncthreads();
  float m = -1e30f;
  for(int c=tid;c<502;c+=256) m = fmaxf(m, pr[c]);
  m = waveMax(m);
  if(lane==0) r4[wv]=m;
  __syncthreads();
  m = fmaxf(fmaxf(r4[0],r4[1]),fmaxf(r4[2],r4[3]));
  float s=0.f;
  for(int c=tid;c<502;c+=256){ float e=expf(pr[c]-m); pr[c]=e; s+=e; }
  s = waveSum(s);
  if(lane==0) r4b[wv]=s;
  __syncthreads();
  float inv = 1.f/(r4b[0]+r4b[1]+r4b[2]+r4b[3]);
  int d = tid&63, g = tid>>6;
  float acc=0.f;
  for(int j=g;j<502;j+=4){
    const float* vp = (j<500) ? V1 + (size_t)j*384
                              : gqkv1 + (size_t)(b2 + (j-500))*1152 + 768;
    acc += pr[j]*vp[h*64+d];
  }
  red[g][d]=acc;
  __syncthreads();
  if(g==0) O[(size_t)bt*384 + h*64 + d] = (red[0][d]+red[1][d]+red[2][d]+red[3][d])*inv;
}

__global__ void merge_seq(const float* __restrict__ src, const float* __restrict__ fused,
                          const int* __restrict__ idx, float* __restrict__ dst, int P){
  int gid = blockIdx.x*256+threadIdx.x;
  if(gid >= 128*P*384) return;
  int j = gid % 384; int rest = gid / 384; int i = rest % P; int b = rest / P;
  int id = idx[b];
  float v;
  if(i == id) v = fused[(size_t)b*384 + j];
  else        v = src[((size_t)b*8 + i + (i>id ? 1:0))*384 + j];
  dst[((size_t)b*8 + i)*384 + j] = v;
}

__global__ void zero_loss6(float* __restrict__ lossBase){
  int b = threadIdx.x;
  if(b<128) lossBase[(size_t)b*9 + 6] = 0.f;
}

__global__ void compact_seq(const float* __restrict__ seq, float* __restrict__ out){
  int gid = blockIdx.x*256+threadIdx.x;
  if(gid >= 256*384) return;
  int j = gid % 384; int r = gid / 384; int b = r>>1; int t = r&1;
  out[gid] = seq[((size_t)b*8 + t)*384 + j];
}

__global__ void logits_k(const float* __restrict__ x2, const float* __restrict__ relmem,
                         const float* __restrict__ seqf, float* __restrict__ out){
  int gid = blockIdx.x*256+threadIdx.x;
  if(gid >= 256*502) return;
  int m = gid % 502; int bt = gid / 502; int b = bt>>1;
  const float* x = x2 + (size_t)bt*384;
  const float* mr = (m<500) ? relmem + (size_t)m*384 : seqf + ((size_t)b*2 + (m-500))*384;
  float s=0.f;
#pragma unroll 8
  for(int d=0;d<384;d++) s = fmaf(x[d], mr[d], s);
  out[gid] = s * 0.05103103630798288f;
}

__global__ void pred_copy(const float* __restrict__ logits, float* __restrict__ out){
  int gid = blockIdx.x*256+threadIdx.x;
  if(gid >= 128*502) return;
  int m = gid % 502; int b = gid / 502;
  out[gid] = logits[((size_t)b*2+1)*502 + m];
}

__global__ __launch_bounds__(256)
void final_ent(const float* __restrict__ L2, float* __restrict__ lossBase){
  int row = blockIdx.x;
  const float* x = L2 + (size_t)row*502;
  int tid = threadIdx.x;
  float m = -1e30f;
  for(int c=tid;c<502;c+=256) m = fmaxf(m, x[c]);
  m = waveMax(m);
  __shared__ float sm[4];
  if((tid&63)==0) sm[tid>>6]=m;
  __syncthreads();
  m = fmaxf(fmaxf(sm[0],sm[1]),fmaxf(sm[2],sm[3]));
  float s=0.f, sx=0.f;
  for(int c=tid;c<502;c+=256){ float e=expf(x[c]-m); s+=e; sx=fmaf(e,x[c],sx); }
  s = waveSum(s); sx = waveSum(sx);
  __shared__ float ps[4], px[4];
  if((tid&63)==0){ ps[tid>>6]=s; px[tid>>6]=sx; }
  __syncthreads();
  if(tid==0){
    float S = ps[0]+ps[1]+ps[2]+ps[3];
    float SX = px[0]+px[1]+px[2]+px[3];
    float ent = (m + logf(S)) - SX/S;
    int b = row>>1, t = row&1;
    lossBase[(size_t)b*9 + 7 + t] = ent;
  }
}

// ---------------- host ----------------
extern "C" void kernel_launch(void* const* d_in, const int* in_sizes, int n_in,
                              void* d_out, int out_size, void* d_ws, size_t ws_size,
                              hipStream_t stream){
  (void)in_sizes; (void)n_in; (void)out_size; (void)ws_size;
  const int*   inputs    = (const int*)  d_in[0];
  const float* emb       = (const float*)d_in[1];
  const float* rel_pos   = (const float*)d_in[2];
  const float* qkv_dyn_w = (const float*)d_in[3];
  const float* qkv_dyn_b = (const float*)d_in[4];
  const float* out_dyn_w = (const float*)d_in[5];
  const float* out_dyn_b = (const float*)d_in[6];
  const float* ln_dyn_g  = (const float*)d_in[7];
  const float* ln_dyn_b  = (const float*)d_in[8];
  const float* conv_w    = (const float*)d_in[9];
  const float* conv_b    = (const float*)d_in[10];
  const float* tl_in_w   = (const float*)d_in[11];
  const float* tl_in_b   = (const float*)d_in[12];
  const float* tl_out_w  = (const float*)d_in[13];
  const float* tl_out_b  = (const float*)d_in[14];
  const float* tl_ln1_g  = (const float*)d_in[15];
  const float* tl_ln1_b  = (const float*)d_in[16];
  const float* tl_ln2_g  = (const float*)d_in[17];
  const float* tl_ln2_b  = (const float*)d_in[18];
  const float* tl_ff1_w  = (const float*)d_in[19];
  const float* tl_ff1_b  = (const float*)d_in[20];
  const float* tl_ff2_w  = (const float*)d_in[21];
  const float* tl_ff2_b  = (const float*)d_in[22];
  const float* fc_score_w= (const float*)d_in[23];
  const float* fc_score_b= (const float*)d_in[24];
  const float* fcq_w     = (const float*)d_in[25];
  const float* fcq_b     = (const float*)d_in[26];
  const float* fck_w     = (const float*)d_in[27];
  const float* fck_b     = (const float*)d_in[28];
  const float* fcv_w     = (const float*)d_in[29];
  const float* fcv_b     = (const float*)d_in[30];
  const float* mha_in_w  = (const float*)d_in[31];
  const float* mha_in_b  = (const float*)d_in[32];
  const float* mha_out_w = (const float*)d_in[33];
  const float* mha_out_b = (const float*)d_in[34];
  const float* lnf1_g    = (const float*)d_in[35];
  const float* lnf1_b    = (const float*)d_in[36];
  const float* lnf2_g    = (const float*)d_in[37];
  const float* lnf2_b    = (const float*)d_in[38];
  const float* ff1_w     = (const float*)d_in[39];
  const float* ff1_b     = (const float*)d_in[40];
  const float* ff2_w     = (const float*)d_in[41];
  const float* ff2_b     = (const float*)d_in[42];

  float* ws = (float*)d_ws;
  size_t off = 0;
  auto Aa = [&](size_t n){ float* p = ws + off; off += n; return p; };
  float* relmem = Aa(192000);
  float* K1mem  = Aa(192000);
  float* V1f    = Aa(192000);
  float* V1l    = Aa(192000);
  float* cb     = Aa(1536);
  float* cb768  = Aa(768);
  float* seqA_  = Aa(393216);
  float* seqB_  = Aa(393216);
  float* fqkv1  = Aa(147456);
  float* gqkv1  = Aa(294912);
  unsigned short* SH = (unsigned short*)Aa(3317760);
  unsigned short* SL = (unsigned short*)Aa(3317760);
  float* pairs  = Aa(688128);
  float* xbuf   = Aa(688128);
  float* qkvbuf = Aa(2064384);
  float* obuf   = Aa(688128);
  float* tmpb   = Aa(688128);
  float* ffbuf  = Aa(2752512);
  int*   idxb   = (int*)Aa(128);
  float* sel    = Aa(49152);
  float* fo     = Aa(49152);
  float* ftmp   = Aa(49152);
  float* fxf    = Aa(49152);
  float* ffused = Aa(49152);
  float* fffb   = Aa(196608);

  // setup-phase temps inside ffbuf
  float* sc512   = ffbuf;                // 2*500*512 = 512000
  float* Cfuse3f = ffbuf + 600000;       // 1152*384 = 442368
  float* Cvkf    = ffbuf + 1100000;      // 147456
  float* Wconvf  = ffbuf + 1300000;      // 589824
  float* VT      = tmpb;                 // 2*192*512 = 196608
  // final-stage aliases
  float* seqf = pairs;
  float* go   = obuf;
  float* gtmp = obuf + 98304;
  float* gx1  = obuf + 196608;
  float* gx2  = obuf + 294912;
  float* logitsb = qkvbuf;

  float* lossBase = (float*)d_out + 128*502;

  // split-arena segment offsets (elements)
  const int o_qkvdyn=0, o_outdyn=442368, o_wconv=589824,
            o_tlin0=1179648, o_tlin1=1622016, o_tlout0=2064384, o_tlout1=2211840,
            o_tlff1_0=2359296, o_tlff1_1=2949120, o_tlff2_0=3538944, o_tlff2_1=4128768,
            o_mhaout=4718592, o_ff1=4866048, o_ff2=5455872, o_cfuse=6045696, o_cvk=6488064;
  const int split_total = 6635520;

  const float s192 = 0.07216878364870322f;  // 1/sqrt(192)

  // ---------- stage 1: relation_mem ----------
  gemm3<0><<<dim3(8,18),256,0,stream>>>(emb,384, qkv_dyn_w,384, qkvbuf,1152, qkv_dyn_b, 500,1152,384, 1.f);
  for(int h=0;h<2;h++)
    gemm3<0><<<dim3(8,8),256,0,stream>>>(qkvbuf + h*192,1152, qkvbuf + 384 + h*192,1152,
           sc512 + (size_t)h*256000,512, nullptr, 500,512,192, s192);
  softmax_rows<<<1000,256,0,stream>>>(sc512, 512, 500);
  vt_k<<<CDIV(2*192*512,256),256,0,stream>>>(qkvbuf, VT);
  for(int h=0;h<2;h++)
    gemm3<0><<<dim3(8,3),256,0,stream>>>(sc512 + (size_t)h*256000,512, VT + h*98304,512,
           obuf + h*192,384, nullptr, 500,192,512, 1.f);
  gemm3<0><<<dim3(8,6),256,0,stream>>>(obuf,384, out_dyn_w,384, xbuf,384, out_dyn_b, 500,384,384, 1.f);
  add_ln<<<500,128,0,stream>>>(emb, xbuf, relmem, ln_dyn_g, ln_dyn_b, 500);

  // ---------- compositions ----------
  gemm_nn<<<dim3(6,6),256,0,stream>>>(mha_in_w,384,            fcq_w,384, Cfuse3f,384,          384,384,384, 1.f);
  gemm_nn<<<dim3(6,6),256,0,stream>>>(mha_in_w + 384*384,384,  fck_w,384, Cfuse3f + 147456,384, 384,384,384, 1.f);
  gemm_nn<<<dim3(6,6),256,0,stream>>>(mha_in_w + 768*384,384,  fcv_w,384, Cfuse3f + 294912,384, 384,384,384, 1.f);
  gemm_nn<<<dim3(6,6),256,0,stream>>>(mha_in_w + 768*384,384,  fck_w,384, Cvkf,384,             384,384,384, 1.f);
  compose_bias<<<6,256,0,stream>>>(mha_in_w, mha_in_b, fcq_b, fck_b, fcv_b, cb);

  // ---------- batch-invariant K/V for fuse/final ----------
  gemm3<0><<<dim3(8,6),256,0,stream>>>(relmem,384, Cfuse3f + 147456,384, K1mem,384, cb+384,  500,384,384, 1.f);
  gemm3<0><<<dim3(8,6),256,0,stream>>>(relmem,384, Cfuse3f + 294912,384, V1f,384,   cb+768,  500,384,384, 1.f);
  gemm3<0><<<dim3(8,6),256,0,stream>>>(relmem,384, Cvkf,384,            V1l,384,   cb+1152, 500,384,384, 1.f);

  prep_conv<<<CDIV(384*384,256),256,0,stream>>>(conv_w, conv_b, Wconvf, cb768);

  // ---------- split all hot-loop weights ----------
  {
    SplitArgs a;
    const float* srcs[NSEG] = { qkv_dyn_w, out_dyn_w, Wconvf, tl_in_w, tl_in_w + 442368,
                                tl_out_w, tl_out_w + 147456, tl_ff1_w, tl_ff1_w + 589824,
                                tl_ff2_w, tl_ff2_w + 589824, mha_out_w, ff1_w, ff2_w,
                                Cfuse3f, Cvkf };
    const int offs[NSEG+1] = { o_qkvdyn, o_outdyn, o_wconv, o_tlin0, o_tlin1, o_tlout0, o_tlout1,
                               o_tlff1_0, o_tlff1_1, o_tlff2_0, o_tlff2_1, o_mhaout, o_ff1, o_ff2,
                               o_cfuse, o_cvk, split_total };
    for(int s=0;s<NSEG;s++){
      a.src[s]=srcs[s]; a.dh[s]=SH+offs[s]; a.dl[s]=SL+offs[s]; a.start[s]=offs[s];
    }
    a.start[NSEG]=split_total;
    split_all<<<CDIV(split_total,256),256,0,stream>>>(a);
  }
  seq_init<<<CDIV(128*8*384,256),256,0,stream>>>(inputs, emb, rel_pos, seqA_);

  float* seqCur = seqA_; float* seqNxt = seqB_;

  // ---------- merge loop ----------
  for(int it=0; it<6; ++it){
    int P = 7 - it;
    int N = 128 * P;
    build_pairs<<<CDIV(N*768,256),256,0,stream>>>(seqCur, rel_pos, pairs, N, P);
    gemm3s<0><<<dim3(N/64,12),256,0,stream>>>(pairs,768, SH+o_wconv,SL+o_wconv,768,
                                              xbuf,768, cb768, N,768,768);
    for(int l=0;l<2;l++){
      int oin  = l? o_tlin1  : o_tlin0;
      int oout = l? o_tlout1 : o_tlout0;
      int of1  = l? o_tlff1_1: o_tlff1_0;
      int of2  = l? o_tlff2_1: o_tlff2_0;
      gemm3s<0><<<dim3(2*N/64,18),256,0,stream>>>(xbuf,384, SH+oin,SL+oin,384,
                                                  qkvbuf,1152, tl_in_b + l*1152, 2*N,1152,384);
      attn2_fused<<<CDIV(2*N,8),512,0,stream>>>(qkvbuf, obuf, 2*N);
      gemm3s<0><<<dim3(2*N/64,6),256,0,stream>>>(obuf,384, SH+oout,SL+oout,384,
                                                 tmpb,384, tl_out_b + l*384, 2*N,384,384);
      add_ln<<<2*N,128,0,stream>>>(xbuf, tmpb, xbuf, tl_ln1_g + l*384, tl_ln1_b + l*384, 2*N);
      gemm3s<1><<<dim3(2*N/64,24),256,0,stream>>>(xbuf,384, SH+of1,SL+of1,384,
                                                  ffbuf,1536, tl_ff1_b + l*1536, 2*N,1536,384);
      gemm3s<0><<<dim3(2*N/64,6),256,0,stream>>>(ffbuf,1536, SH+of2,SL+of2,1536,
                                                 tmpb,384, tl_ff2_b + l*384, 2*N,384,1536);
      add_ln<<<2*N,128,0,stream>>>(xbuf, tmpb, xbuf, tl_ln2_g + l*384, tl_ln2_b + l*384, 2*N);
    }
    score_select<<<128,256,0,stream>>>(xbuf, fc_score_w, fc_score_b, P, idxb, lossBase + it, sel);
    gemm3s<0><<<dim3(2,18),256,0,stream>>>(sel,384, SH+o_cfuse,SL+o_cfuse,384,
                                           fqkv1,1152, cb, 128,1152,384);
    flash_fuse<<<768,256,0,stream>>>(fqkv1, K1mem, V1f, fo);
    gemm3s<0><<<dim3(2,6),256,0,stream>>>(fo,384, SH+o_mhaout,SL+o_mhaout,384,
                                          ftmp,384, mha_out_b, 128,384,384);
    add_ln<<<128,128,0,stream>>>(sel, ftmp, fxf, lnf1_g, lnf1_b, 128);
    gemm3s<1><<<dim3(2,24),256,0,stream>>>(fxf,384, SH+o_ff1,SL+o_ff1,384,
                                           fffb,1536, ff1_b, 128,1536,384);
    gemm3s<0><<<dim3(2,6),256,0,stream>>>(fffb,1536, SH+o_ff2,SL+o_ff2,1536,
                                          ftmp,384, ff2_b, 128,384,1536);
    add_ln<<<128,128,0,stream>>>(fxf, ftmp, ffused, lnf2_g, lnf2_b, 128);
    merge_seq<<<CDIV(128*P*384,256),256,0,stream>>>(seqCur, ffused, idxb, seqNxt, P);
    float* t_ = seqCur; seqCur = seqNxt; seqNxt = t_;
  }
  zero_loss6<<<1,128,0,stream>>>(lossBase);

  // ---------- final stage (Lf = 2) ----------
  compact_seq<<<CDIV(256*384,256),256,0,stream>>>(seqCur, seqf);
  gemm3s<0><<<dim3(4,12),256,0,stream>>>(seqf,384, SH+o_cfuse,SL+o_cfuse,384,
                                         gqkv1,1152, cb, 256,768,384);
  gemm3s<0><<<dim3(4,6),256,0,stream>>>(seqf,384, SH+o_cvk,SL+o_cvk,384,
                                        gqkv1+768,1152, cb+1152, 256,384,384);
  flash_fin<<<1536,256,0,stream>>>(gqkv1, K1mem, V1l, go);
  gemm3s<0><<<dim3(4,6),256,0,stream>>>(go,384, SH+o_mhaout,SL+o_mhaout,384,
                                        gtmp,384, mha_out_b, 256,384,384);
  add_ln<<<256,128,0,stream>>>(seqf, gtmp, gx1, lnf1_g, lnf1_b, 256);
  gemm3s<1><<<dim3(4,24),256,0,stream>>>(gx1,384, SH+o_ff1,SL+o_ff1,384,
                                         ffbuf,1536, ff1_b, 256,1536,384);
  gemm3s<0><<<dim3(4,6),256,0,stream>>>(ffbuf,1536, SH+o_ff2,SL+o_ff2,1536,
                                        gtmp,384, ff2_b, 256,384,1536);
  add_ln<<<256,128,0,stream>>>(gx1, gtmp, gx2, lnf2_g, lnf2_b, 256);
  logits_k<<<CDIV(256*502,256),256,0,stream>>>(gx2, relmem, seqf, logitsb);
  pred_copy<<<CDIV(128*502,256),256,0,stream>>>(logitsb, (float*)d_out);
  final_ent<<<256,256,0,stream>>>(logitsb, lossBase);
}

// Round 4
// 3277.878 us; speedup vs baseline: 1.0701x; 1.0701x over previous
//
#include <hip/hip_runtime.h>

#define CDIV(a,b) (((a)+(b)-1)/(b))

typedef __bf16 bf16x8 __attribute__((ext_vector_type(8)));
typedef float  f32x4  __attribute__((ext_vector_type(4)));
#define MFMA16(a,b,c) __builtin_amdgcn_mfma_f32_16x16x32_bf16(a,b,c,0,0,0)

// ---------------- wave/block reductions ----------------
__device__ __forceinline__ float waveSum(float v){
#pragma unroll
  for(int o=32;o;o>>=1) v += __shfl_xor(v,o);
  return v;
}
__device__ __forceinline__ float waveMax(float v){
#pragma unroll
  for(int o=32;o;o>>=1) v = fmaxf(v,__shfl_xor(v,o));
  return v;
}

// ---------------- bf16 split helpers ----------------
__device__ __forceinline__ unsigned short f2bf(float f){
  unsigned u = __float_as_uint(f);
  u += 0x7FFFu + ((u>>16)&1u);
  return (unsigned short)(u>>16);
}
__device__ __forceinline__ float bf2f(unsigned short h){
  return __uint_as_float(((unsigned)h)<<16);
}
__device__ __forceinline__ void pack8(const float4& x, const float4& y,
                                      uint4& hi, uint4& lo){
  float v[8] = {x.x,x.y,x.z,x.w,y.x,y.y,y.z,y.w};
  unsigned short h[8], l[8];
#pragma unroll
  for(int i=0;i<8;i++){
    h[i] = f2bf(v[i]);
    l[i] = f2bf(v[i] - bf2f(h[i]));
  }
  hi = make_uint4((unsigned)h[0]|((unsigned)h[1]<<16), (unsigned)h[2]|((unsigned)h[3]<<16),
                  (unsigned)h[4]|((unsigned)h[5]<<16), (unsigned)h[6]|((unsigned)h[7]<<16));
  lo = make_uint4((unsigned)l[0]|((unsigned)l[1]<<16), (unsigned)l[2]|((unsigned)l[3]<<16),
                  (unsigned)l[4]|((unsigned)l[5]<<16), (unsigned)l[6]|((unsigned)l[7]<<16));
}

__device__ __forceinline__ bf16x8 ldsfrag(const unsigned short* base, int row, int kb){
  int off = (row<<7) + (kb<<1);
  off ^= (row&7)<<4;
  return *reinterpret_cast<const bf16x8*>(reinterpret_cast<const char*>(base) + off);
}

// ---------------- MFMA bf16x3 NT GEMM, f32 W (setup paths) ----------------
template<int ACT>
__global__ __launch_bounds__(256)
void gemm3(const float* __restrict__ A, int lda,
           const float* __restrict__ W, int ldw,
           float* __restrict__ C, int ldc,
           const float* __restrict__ bias, int M, int N, int K, float scale)
{
  __shared__ unsigned short AsH[64*64];
  __shared__ unsigned short AsL[64*64];
  __shared__ unsigned short WsH[64*64];
  __shared__ unsigned short WsL[64*64];
  const int tid  = threadIdx.x;
  const int bm   = blockIdx.x*64, bn = blockIdx.y*64;
  const int lane = tid & 63, wid = tid >> 6;
  const int wm   = (wid&1)*32, wn = (wid>>1)*32;
  const int r0   = tid>>3;
  const int kq   = (tid&7)*8;

  float4 gA[2][2], gW[2][2];
  auto loadG = [&](int k0){
#pragma unroll
    for(int i=0;i<2;i++){
      int r = r0 + i*32;
      if(bm+r < M){
        const float* pa = A + (size_t)(bm+r)*lda + k0 + kq;
        gA[i][0] = *reinterpret_cast<const float4*>(pa);
        gA[i][1] = *reinterpret_cast<const float4*>(pa+4);
      } else {
        gA[i][0] = make_float4(0.f,0.f,0.f,0.f);
        gA[i][1] = make_float4(0.f,0.f,0.f,0.f);
      }
      const float* pw = W + (size_t)(bn+r)*ldw + k0 + kq;
      gW[i][0] = *reinterpret_cast<const float4*>(pw);
      gW[i][1] = *reinterpret_cast<const float4*>(pw+4);
    }
  };
  auto writeL = [&](){
#pragma unroll
    for(int i=0;i<2;i++){
      int r = r0 + i*32;
      int off = (r<<7) + (tid&7)*16;
      off ^= (r&7)<<4;
      uint4 hi, lo;
      pack8(gA[i][0], gA[i][1], hi, lo);
      *reinterpret_cast<uint4*>(reinterpret_cast<char*>(AsH) + off) = hi;
      *reinterpret_cast<uint4*>(reinterpret_cast<char*>(AsL) + off) = lo;
      pack8(gW[i][0], gW[i][1], hi, lo);
      *reinterpret_cast<uint4*>(reinterpret_cast<char*>(WsH) + off) = hi;
      *reinterpret_cast<uint4*>(reinterpret_cast<char*>(WsL) + off) = lo;
    }
  };

  f32x4 acc[2][2];
#pragma unroll
  for(int mi=0;mi<2;mi++)
#pragma unroll
    for(int ni=0;ni<2;ni++) acc[mi][ni] = f32x4{0.f,0.f,0.f,0.f};

  loadG(0);
  for(int k0=0; k0<K; k0+=64){
    __syncthreads();
    writeL();
    __syncthreads();
    if(k0+64 < K) loadG(k0+64);
    const int lk = (lane>>4)*8;
    const int lc = lane&15;
#pragma unroll
    for(int kk=0; kk<2; kk++){
      int kb = kk*32 + lk;
      bf16x8 aH[2], aL[2], bH[2], bL[2];
#pragma unroll
      for(int m=0;m<2;m++){
        aH[m] = ldsfrag(AsH, wm + lc + m*16, kb);
        aL[m] = ldsfrag(AsL, wm + lc + m*16, kb);
        bH[m] = ldsfrag(WsH, wn + lc + m*16, kb);
        bL[m] = ldsfrag(WsL, wn + lc + m*16, kb);
      }
#pragma unroll
      for(int mi=0;mi<2;mi++)
#pragma unroll
        for(int ni=0;ni<2;ni++){
          acc[mi][ni] = MFMA16(aH[mi], bH[ni], acc[mi][ni]);
          acc[mi][ni] = MFMA16(aH[mi], bL[ni], acc[mi][ni]);
          acc[mi][ni] = MFMA16(aL[mi], bH[ni], acc[mi][ni]);
        }
    }
  }

  const int lr = lane>>4, lc = lane&15;
#pragma unroll
  for(int mi=0;mi<2;mi++)
#pragma unroll
    for(int ni=0;ni<2;ni++)
#pragma unroll
      for(int r=0;r<4;r++){
        int row = bm + wm + mi*16 + lr*4 + r;
        if(row>=M) continue;
        int col = bn + wn + ni*16 + lc;
        float v = acc[mi][ni][r]*scale + (bias ? bias[col] : 0.f);
        if(ACT==1) v = 0.5f*v*(1.f+erff(v*0.70710678118654752f));
        C[(size_t)row*ldc+col] = v;
      }
}

// ---------------- MFMA bf16x3 NT GEMM, pre-split W (hot path) ----------------
template<int ACT>
__global__ __launch_bounds__(256)
void gemm3s(const float* __restrict__ A, int lda,
            const unsigned short* __restrict__ WH,
            const unsigned short* __restrict__ WL, int ldw,
            float* __restrict__ C, int ldc,
            const float* __restrict__ bias, int M, int N, int K)
{
  __shared__ unsigned short AsH[64*64];
  __shared__ unsigned short AsL[64*64];
  __shared__ unsigned short WsH[64*64];
  __shared__ unsigned short WsL[64*64];
  const int tid  = threadIdx.x;
  const int bm   = blockIdx.x*64, bn = blockIdx.y*64;
  const int lane = tid & 63, wid = tid >> 6;
  const int wm   = (wid&1)*32, wn = (wid>>1)*32;
  const int r0   = tid>>3;
  const int kq   = (tid&7)*8;

  float4 gA[2][2]; uint4 gWH[2], gWL[2];
  auto loadG = [&](int k0){
#pragma unroll
    for(int i=0;i<2;i++){
      int r = r0 + i*32;
      if(bm+r < M){
        const float* pa = A + (size_t)(bm+r)*lda + k0 + kq;
        gA[i][0] = *reinterpret_cast<const float4*>(pa);
        gA[i][1] = *reinterpret_cast<const float4*>(pa+4);
      } else {
        gA[i][0] = make_float4(0.f,0.f,0.f,0.f);
        gA[i][1] = make_float4(0.f,0.f,0.f,0.f);
      }
      gWH[i] = *reinterpret_cast<const uint4*>(WH + (size_t)(bn+r)*ldw + k0 + kq);
      gWL[i] = *reinterpret_cast<const uint4*>(WL + (size_t)(bn+r)*ldw + k0 + kq);
    }
  };
  auto writeL = [&](){
#pragma unroll
    for(int i=0;i<2;i++){
      int r = r0 + i*32;
      int off = (r<<7) + (tid&7)*16;
      off ^= (r&7)<<4;
      uint4 hi, lo;
      pack8(gA[i][0], gA[i][1], hi, lo);
      *reinterpret_cast<uint4*>(reinterpret_cast<char*>(AsH) + off) = hi;
      *reinterpret_cast<uint4*>(reinterpret_cast<char*>(AsL) + off) = lo;
      *reinterpret_cast<uint4*>(reinterpret_cast<char*>(WsH) + off) = gWH[i];
      *reinterpret_cast<uint4*>(reinterpret_cast<char*>(WsL) + off) = gWL[i];
    }
  };

  f32x4 acc[2][2];
#pragma unroll
  for(int mi=0;mi<2;mi++)
#pragma unroll
    for(int ni=0;ni<2;ni++) acc[mi][ni] = f32x4{0.f,0.f,0.f,0.f};

  loadG(0);
  for(int k0=0; k0<K; k0+=64){
    __syncthreads();
    writeL();
    __syncthreads();
    if(k0+64 < K) loadG(k0+64);
    const int lk = (lane>>4)*8;
    const int lc = lane&15;
#pragma unroll
    for(int kk=0; kk<2; kk++){
      int kb = kk*32 + lk;
      bf16x8 aH[2], aL[2], bH[2], bL[2];
#pragma unroll
      for(int m=0;m<2;m++){
        aH[m] = ldsfrag(AsH, wm + lc + m*16, kb);
        aL[m] = ldsfrag(AsL, wm + lc + m*16, kb);
        bH[m] = ldsfrag(WsH, wn + lc + m*16, kb);
        bL[m] = ldsfrag(WsL, wn + lc + m*16, kb);
      }
#pragma unroll
      for(int mi=0;mi<2;mi++)
#pragma unroll
        for(int ni=0;ni<2;ni++){
          acc[mi][ni] = MFMA16(aH[mi], bH[ni], acc[mi][ni]);
          acc[mi][ni] = MFMA16(aH[mi], bL[ni], acc[mi][ni]);
          acc[mi][ni] = MFMA16(aL[mi], bH[ni], acc[mi][ni]);
        }
    }
  }

  const int lr = lane>>4, lc = lane&15;
#pragma unroll
  for(int mi=0;mi<2;mi++)
#pragma unroll
    for(int ni=0;ni<2;ni++)
#pragma unroll
      for(int r=0;r<4;r++){
        int row = bm + wm + mi*16 + lr*4 + r;
        if(row>=M) continue;
        int col = bn + wn + ni*16 + lc;
        float v = acc[mi][ni][r] + (bias ? bias[col] : 0.f);
        if(ACT==1) v = 0.5f*v*(1.f+erff(v*0.70710678118654752f));
        C[(size_t)row*ldc+col] = v;
      }
}

// ---------------- f32 NN GEMM (setup compositions) ----------------
__global__ __launch_bounds__(256)
void gemm_nn(const float* __restrict__ A, int lda,
             const float* __restrict__ Bm, int ldb,
             float* __restrict__ C, int ldc,
             int M, int N, int K, float scale)
{
  __shared__ float As[16][68];
  __shared__ float Bs[16][68];
  const int bm = blockIdx.x*64, bn = blockIdx.y*64;
  const int tid = threadIdx.x;
  const int lr = tid>>2;
  const int kq = (tid&3)<<2;
  const int kr = tid>>4;
  const int nq = (tid&15)<<2;
  const int tx = tid&15, ty = tid>>4;
  float acc[4][4] = {};
  for(int k0=0;k0<K;k0+=16){
    float4 av = make_float4(0.f,0.f,0.f,0.f), bv = make_float4(0.f,0.f,0.f,0.f);
    if(bm+lr < M && k0+kq < K) av = *reinterpret_cast<const float4*>(A + (size_t)(bm+lr)*lda + k0+kq);
    if(k0+kr < K && bn+nq < N) bv = *reinterpret_cast<const float4*>(Bm + (size_t)(k0+kr)*ldb + bn+nq);
    As[kq+0][lr]=av.x; As[kq+1][lr]=av.y; As[kq+2][lr]=av.z; As[kq+3][lr]=av.w;
    Bs[kr][nq+0]=bv.x; Bs[kr][nq+1]=bv.y; Bs[kr][nq+2]=bv.z; Bs[kr][nq+3]=bv.w;
    __syncthreads();
#pragma unroll
    for(int k=0;k<16;k++){
      float4 a4 = *reinterpret_cast<const float4*>(&As[k][ty<<2]);
      float4 b4 = *reinterpret_cast<const float4*>(&Bs[k][tx<<2]);
      float aa[4]={a4.x,a4.y,a4.z,a4.w};
      float bb[4]={b4.x,b4.y,b4.z,b4.w};
#pragma unroll
      for(int i=0;i<4;i++)
#pragma unroll
        for(int j=0;j<4;j++) acc[i][j] = fmaf(aa[i],bb[j],acc[i][j]);
    }
    __syncthreads();
  }
#pragma unroll
  for(int i=0;i<4;i++){
    int row = bm + (ty<<2) + i;
    if(row>=M) continue;
#pragma unroll
    for(int j=0;j<4;j++){
      int col = bn + (tx<<2) + j;
      if(col>=N) continue;
      C[(size_t)row*ldc+col]=acc[i][j]*scale;
    }
  }
}

// ---------------- LayerNorm(x + t), row-per-block ----------------
__global__ __launch_bounds__(128)
void add_ln(const float* __restrict__ X, const float* __restrict__ T,
            float* __restrict__ O, const float* __restrict__ g,
            const float* __restrict__ be, int M)
{
  int row = blockIdx.x;
  if(row>=M) return;
  const float* x = X + (size_t)row*384;
  const float* t = T + (size_t)row*384;
  float* o = O + (size_t)row*384;
  int tid = threadIdx.x;
  float v[3]; float s=0.f;
#pragma unroll
  for(int i=0;i<3;i++){ int c = tid + i*128; v[i] = x[c] + t[c]; s += v[i]; }
  s = waveSum(s);
  __shared__ float p1[2];
  if((tid&63)==0) p1[tid>>6]=s;
  __syncthreads();
  float mean = (p1[0]+p1[1])*(1.f/384.f);
  float vs=0.f;
#pragma unroll
  for(int i=0;i<3;i++){ float d=v[i]-mean; vs += d*d; }
  vs = waveSum(vs);
  __shared__ float p2[2];
  if((tid&63)==0) p2[tid>>6]=vs;
  __syncthreads();
  float rstd = rsqrtf((p2[0]+p2[1])*(1.f/384.f) + 1e-5f);
#pragma unroll
  for(int i=0;i<3;i++){ int c = tid + i*128; o[c] = (v[i]-mean)*rstd*g[c] + be[c]; }
}

// ---------------- row softmax with ld + zero-pad tail ----------------
__global__ __launch_bounds__(256)
void softmax_rows(float* __restrict__ X, int ld, int cols)
{
  float* x = X + (size_t)blockIdx.x*ld;
  int tid = threadIdx.x;
  float m = -1e30f;
  for(int c=tid;c<cols;c+=256) m = fmaxf(m, x[c]);
  m = waveMax(m);
  __shared__ float sm[4];
  if((tid&63)==0) sm[tid>>6]=m;
  __syncthreads();
  m = fmaxf(fmaxf(sm[0],sm[1]),fmaxf(sm[2],sm[3]));
  float s=0.f;
  for(int c=tid;c<cols;c+=256){ float e = expf(x[c]-m); x[c]=e; s+=e; }
  s = waveSum(s);
  __shared__ float ss[4];
  if((tid&63)==0) ss[tid>>6]=s;
  __syncthreads();
  s = ss[0]+ss[1]+ss[2]+ss[3];
  float inv = 1.f/s;
  for(int c=tid;c<cols;c+=256) x[c]*=inv;
  for(int c=cols+tid;c<ld;c+=256) x[c]=0.f;
}

// ---------------- setup kernels ----------------
__global__ void prep_conv(const float* __restrict__ cw, const float* __restrict__ cb,
                          float* __restrict__ Wc, float* __restrict__ cb768){
  int gid = blockIdx.x*256+threadIdx.x;
  if(gid >= 384*384) return;
  int i = gid % 384, o = gid / 384;
  const float* w = cw + (size_t)gid*3;
  Wc[(size_t)o*768 + i]            = w[1];
  Wc[(size_t)o*768 + 384 + i]      = w[2];
  Wc[(size_t)(384+o)*768 + i]      = w[0];
  Wc[(size_t)(384+o)*768 + 384 + i]= w[1];
  if(gid < 768) cb768[gid] = cb[gid % 384];
}

__global__ void vt_k(const float* __restrict__ qkv, float* __restrict__ VT){
  int gid = blockIdx.x*256+threadIdx.x;
  if(gid >= 2*192*512) return;
  int k = gid & 511; int n = (gid>>9) % 192; int h = gid / 98304;
  VT[gid] = (k<500) ? qkv[(size_t)k*1152 + 768 + h*192 + n] : 0.f;
}

__global__ void compose_bias(const float* __restrict__ inw, const float* __restrict__ inb,
                             const float* __restrict__ qb, const float* __restrict__ kb,
                             const float* __restrict__ vb, float* __restrict__ cb){
  int gid = blockIdx.x*256+threadIdx.x;
  if(gid>=1536) return;
  int seg = gid/384, i = gid%384;
  const float* wrow; const float* bsrc; float b2;
  if(seg==0){ wrow=inw + (size_t)i*384;       bsrc=qb; b2=inb[i]; }
  else if(seg==1){ wrow=inw + (size_t)(384+i)*384; bsrc=kb; b2=inb[384+i]; }
  else if(seg==2){ wrow=inw + (size_t)(768+i)*384; bsrc=vb; b2=inb[768+i]; }
  else          { wrow=inw + (size_t)(768+i)*384; bsrc=kb; b2=inb[768+i]; }
  float s=0.f;
  for(int t=0;t<384;t++) s = fmaf(wrow[t], bsrc[t], s);
  cb[gid] = s + b2;
}

#define NSEG 16
struct SplitArgs {
  const float* src[NSEG];
  unsigned short* dh[NSEG];
  unsigned short* dl[NSEG];
  int start[NSEG+1];
};
__global__ void split_all(SplitArgs a){
  int gid = blockIdx.x*256+threadIdx.x;
  if(gid >= a.start[NSEG]) return;
  int s=0;
  while(s<NSEG-1 && gid >= a.start[s+1]) s++;
  int off = gid - a.start[s];
  float v = a.src[s][off];
  unsigned short h = f2bf(v);
  a.dh[s][off] = h;
  a.dl[s][off] = f2bf(v - bf2f(h));
}

__global__ void seq_init(const int* __restrict__ inp, const float* __restrict__ emb,
                         const float* __restrict__ rp, float* __restrict__ seq){
  int gid = blockIdx.x*256+threadIdx.x;
  if(gid >= 128*8*384) return;
  int j = gid % 384; int l = (gid/384) & 7; int b = gid / 3072;
  int tok = inp[b*8 + l];
  seq[gid] = emb[(size_t)tok*384 + j] + rp[l*384 + j];
}

// ---------------- merge-loop kernels ----------------
__global__ void build_pairs(const float* __restrict__ seq, const float* __restrict__ rp,
                            float* __restrict__ pairs, int N, int P){
  int gid = blockIdx.x*256+threadIdx.x;
  if(gid >= N*768) return;
  int c = gid % 768; int n = gid / 768;
  int t = c / 384; int j = c % 384;
  int i = n % P; int b = n / P;
  pairs[gid] = seq[((size_t)b*8 + i + t)*384 + j] + rp[t*384 + j];
}

// fused len-2 attention: one wave per (pair,t) row, 8 waves/block
__global__ __launch_bounds__(512)
void attn2_fused(const float* __restrict__ QKV, float* __restrict__ O, int rows){
  int w = threadIdx.x >> 6, lane = threadIdx.x & 63;
  int r = blockIdx.x*8 + w;
  if(r >= rows) return;
  const float* qr  = QKV + (size_t)r*1152;
  const float* kr0 = QKV + (size_t)(r & ~1)*1152 + 384;
  const float* vr0 = QKV + (size_t)(r & ~1)*1152 + 768;
  float* o = O + (size_t)r*384;
  const float sc = 0.1020620726159658f;   // 1/sqrt(96)
#pragma unroll
  for(int h=0;h<4;h++){
    const float* qp  = qr  + h*96;
    const float* k0p = kr0 + h*96;
    const float* k1p = k0p + 1152;
    const float* v0p = vr0 + h*96;
    const float* v1p = v0p + 1152;
    float qa = qp[lane];
    float s0 = qa*k0p[lane];
    float s1 = qa*k1p[lane];
    if(lane<32){
      float qb = qp[64+lane];
      s0 += qb*k0p[64+lane];
      s1 += qb*k1p[64+lane];
    }
    s0 = waveSum(s0)*sc; s1 = waveSum(s1)*sc;
    float mm = fmaxf(s0,s1);
    float e0 = expf(s0-mm), e1 = expf(s1-mm);
    float inv = 1.f/(e0+e1);
    e0*=inv; e1*=inv;
    o[h*96+lane] = e0*v0p[lane] + e1*v1p[lane];
    if(lane<32) o[h*96+64+lane] = e0*v0p[64+lane] + e1*v1p[64+lane];
  }
}

// fused score + argmax + entropy + gather; one block per batch
__global__ __launch_bounds__(256)
void score_select(const float* __restrict__ X, const float* __restrict__ w,
                  const float* __restrict__ b0, int P, int* __restrict__ idxb,
                  float* __restrict__ lossSlot, float* __restrict__ sel){
  int b = blockIdx.x;
  int tid = threadIdx.x, lane = tid&63, wv = tid>>6;
  __shared__ float scs[8];
  __shared__ int sidx;
  for(int pi=wv; pi<P; pi+=4){
    const float* x = X + (((size_t)b*P+pi)*2+1)*384;
    float s=0.f;
#pragma unroll
    for(int i=0;i<6;i++){ int c = lane + i*64; s = fmaf(x[c], w[c], s); }
    s = waveSum(s);
    if(lane==0) scs[pi] = 1.f/(1.f+expf(-(s + b0[0])));
  }
  __syncthreads();
  if(tid==0){
    float m = scs[0]; int am = 0;
    for(int i=1;i<P;i++){ float v=scs[i]; if(v>m){m=v;am=i;} }
    float z=0.f, sx=0.f;
    for(int i=0;i<P;i++){ float e=expf(scs[i]-m); z+=e; sx=fmaf(e,scs[i],sx); }
    lossSlot[(size_t)b*9] = (m + logf(z)) - sx/z;
    idxb[b] = am;
    sidx = am;
  }
  __syncthreads();
  const float* src = X + (((size_t)b*P+sidx)*2+1)*384;
  for(int c=tid;c<384;c+=256) sel[(size_t)b*384+c] = src[c];
}

// ---------------- wave-per-head attention over 500 mem keys + NEXTRA per-batch keys ----
// block = query row; 6 waves = 6 heads; no cross-lane reduce in score loop.
template<int NEXTRA>
__global__ __launch_bounds__(384)
void attn_mem(const float* __restrict__ qkv1,   // [R][1152] q|k|v rows
              const float* __restrict__ K1,     // [500][384]
              const float* __restrict__ V1,     // [500][384]
              float* __restrict__ O)            // [R][384]
{
  const int NK = 500 + NEXTRA;
  const int r = blockIdx.x;
  const int h = threadIdx.x >> 6, lane = threadIdx.x & 63;
  const int rbase = (NEXTRA==2) ? (r & ~1) : r;
  __shared__ float P[6][504];
  __shared__ float qs[6][64];
  qs[h][lane] = qkv1[(size_t)r*1152 + h*64 + lane];
  __syncthreads();
  // scores: one key per lane, serial 64-FMA dot (no shuffles)
  for(int j=lane; j<NK; j+=64){
    const float* kp = (j<500) ? K1 + (size_t)j*384 + h*64
                              : qkv1 + (size_t)(rbase + (j-500))*1152 + 384 + h*64;
    float s=0.f;
#pragma unroll
    for(int d4=0; d4<16; d4++){
      float4 k4 = *reinterpret_cast<const float4*>(kp + d4*4);
      s = fmaf(qs[h][d4*4+0], k4.x, s);
      s = fmaf(qs[h][d4*4+1], k4.y, s);
      s = fmaf(qs[h][d4*4+2], k4.z, s);
      s = fmaf(qs[h][d4*4+3], k4.w, s);
    }
    P[h][j] = s*0.125f;
  }
  __syncthreads();
  // wave-local softmax over the head's score row
  float m = -1e30f;
  for(int j=lane;j<NK;j+=64) m = fmaxf(m, P[h][j]);
  m = waveMax(m);
  float s=0.f;
  for(int j=lane;j<NK;j+=64){ float e=expf(P[h][j]-m); P[h][j]=e; s+=e; }
  s = waveSum(s);
  float inv = 1.f/s;
  __syncthreads();
  // PV: lane = output dim, coalesced V reads
  float acc=0.f;
#pragma unroll 8
  for(int j=0;j<500;j++) acc = fmaf(P[h][j], V1[(size_t)j*384 + h*64 + lane], acc);
#pragma unroll
  for(int e=0;e<NEXTRA;e++)
    acc = fmaf(P[h][500+e], qkv1[(size_t)(rbase+e)*1152 + 768 + h*64 + lane], acc);
  O[(size_t)r*384 + h*64 + lane] = acc*inv;
}

__global__ void merge_seq(const float* __restrict__ src, const float* __restrict__ fused,
                          const int* __restrict__ idx, float* __restrict__ dst, int P){
  int gid = blockIdx.x*256+threadIdx.x;
  if(gid >= 128*P*384) return;
  int j = gid % 384; int rest = gid / 384; int i = rest % P; int b = rest / P;
  int id = idx[b];
  float v;
  if(i == id) v = fused[(size_t)b*384 + j];
  else        v = src[((size_t)b*8 + i + (i>id ? 1:0))*384 + j];
  dst[((size_t)b*8 + i)*384 + j] = v;
}

__global__ void zero_loss6(float* __restrict__ lossBase){
  int b = threadIdx.x;
  if(b<128) lossBase[(size_t)b*9 + 6] = 0.f;
}

__global__ void compact_seq(const float* __restrict__ seq, float* __restrict__ out){
  int gid = blockIdx.x*256+threadIdx.x;
  if(gid >= 256*384) return;
  int j = gid % 384; int r = gid / 384; int b = r>>1; int t = r&1;
  out[gid] = seq[((size_t)b*8 + t)*384 + j];
}

__global__ void logits_k(const float* __restrict__ x2, const float* __restrict__ relmem,
                         const float* __restrict__ seqf, float* __restrict__ out){
  int gid = blockIdx.x*256+threadIdx.x;
  if(gid >= 256*502) return;
  int m = gid % 502; int bt = gid / 502; int b = bt>>1;
  const float* x = x2 + (size_t)bt*384;
  const float* mr = (m<500) ? relmem + (size_t)m*384 : seqf + ((size_t)b*2 + (m-500))*384;
  float s=0.f;
#pragma unroll 8
  for(int d=0;d<384;d++) s = fmaf(x[d], mr[d], s);
  out[gid] = s * 0.05103103630798288f;
}

__global__ void pred_copy(const float* __restrict__ logits, float* __restrict__ out){
  int gid = blockIdx.x*256+threadIdx.x;
  if(gid >= 128*502) return;
  int m = gid % 502; int b = gid / 502;
  out[gid] = logits[((size_t)b*2+1)*502 + m];
}

__global__ __launch_bounds__(256)
void final_ent(const float* __restrict__ L2, float* __restrict__ lossBase){
  int row = blockIdx.x;
  const float* x = L2 + (size_t)row*502;
  int tid = threadIdx.x;
  float m = -1e30f;
  for(int c=tid;c<502;c+=256) m = fmaxf(m, x[c]);
  m = waveMax(m);
  __shared__ float sm[4];
  if((tid&63)==0) sm[tid>>6]=m;
  __syncthreads();
  m = fmaxf(fmaxf(sm[0],sm[1]),fmaxf(sm[2],sm[3]));
  float s=0.f, sx=0.f;
  for(int c=tid;c<502;c+=256){ float e=expf(x[c]-m); s+=e; sx=fmaf(e,x[c],sx); }
  s = waveSum(s); sx = waveSum(sx);
  __shared__ float ps[4], px[4];
  if((tid&63)==0){ ps[tid>>6]=s; px[tid>>6]=sx; }
  __syncthreads();
  if(tid==0){
    float S = ps[0]+ps[1]+ps[2]+ps[3];
    float SX = px[0]+px[1]+px[2]+px[3];
    float ent = (m + logf(S)) - SX/S;
    int b = row>>1, t = row&1;
    lossBase[(size_t)b*9 + 7 + t] = ent;
  }
}

// ---------------- host ----------------
extern "C" void kernel_launch(void* const* d_in, const int* in_sizes, int n_in,
                              void* d_out, int out_size, void* d_ws, size_t ws_size,
                              hipStream_t stream){
  (void)in_sizes; (void)n_in; (void)out_size; (void)ws_size;
  const int*   inputs    = (const int*)  d_in[0];
  const float* emb       = (const float*)d_in[1];
  const float* rel_pos   = (const float*)d_in[2];
  const float* qkv_dyn_w = (const float*)d_in[3];
  const float* qkv_dyn_b = (const float*)d_in[4];
  const float* out_dyn_w = (const float*)d_in[5];
  const float* out_dyn_b = (const float*)d_in[6];
  const float* ln_dyn_g  = (const float*)d_in[7];
  const float* ln_dyn_b  = (const float*)d_in[8];
  const float* conv_w    = (const float*)d_in[9];
  const float* conv_b    = (const float*)d_in[10];
  const float* tl_in_w   = (const float*)d_in[11];
  const float* tl_in_b   = (const float*)d_in[12];
  const float* tl_out_w  = (const float*)d_in[13];
  const float* tl_out_b  = (const float*)d_in[14];
  const float* tl_ln1_g  = (const float*)d_in[15];
  const float* tl_ln1_b  = (const float*)d_in[16];
  const float* tl_ln2_g  = (const float*)d_in[17];
  const float* tl_ln2_b  = (const float*)d_in[18];
  const float* tl_ff1_w  = (const float*)d_in[19];
  const float* tl_ff1_b  = (const float*)d_in[20];
  const float* tl_ff2_w  = (const float*)d_in[21];
  const float* tl_ff2_b  = (const float*)d_in[22];
  const float* fc_score_w= (const float*)d_in[23];
  const float* fc_score_b= (const float*)d_in[24];
  const float* fcq_w     = (const float*)d_in[25];
  const float* fcq_b     = (const float*)d_in[26];
  const float* fck_w     = (const float*)d_in[27];
  const float* fck_b     = (const float*)d_in[28];
  const float* fcv_w     = (const float*)d_in[29];
  const float* fcv_b     = (const float*)d_in[30];
  const float* mha_in_w  = (const float*)d_in[31];
  const float* mha_in_b  = (const float*)d_in[32];
  const float* mha_out_w = (const float*)d_in[33];
  const float* mha_out_b = (const float*)d_in[34];
  const float* lnf1_g    = (const float*)d_in[35];
  const float* lnf1_b    = (const float*)d_in[36];
  const float* lnf2_g    = (const float*)d_in[37];
  const float* lnf2_b    = (const float*)d_in[38];
  const float* ff1_w     = (const float*)d_in[39];
  const float* ff1_b     = (const float*)d_in[40];
  const float* ff2_w     = (const float*)d_in[41];
  const float* ff2_b     = (const float*)d_in[42];

  float* ws = (float*)d_ws;
  size_t off = 0;
  auto Aa = [&](size_t n){ float* p = ws + off; off += n; return p; };
  float* relmem = Aa(192000);
  float* K1mem  = Aa(192000);
  float* V1f    = Aa(192000);
  float* V1l    = Aa(192000);
  float* cb     = Aa(1536);
  float* cb768  = Aa(768);
  float* seqA_  = Aa(393216);
  float* seqB_  = Aa(393216);
  float* fqkv1  = Aa(147456);
  float* gqkv1  = Aa(294912);
  unsigned short* SH = (unsigned short*)Aa(3317760);
  unsigned short* SL = (unsigned short*)Aa(3317760);
  float* pairs  = Aa(688128);
  float* xbuf   = Aa(688128);
  float* qkvbuf = Aa(2064384);
  float* obuf   = Aa(688128);
  float* tmpb   = Aa(688128);
  float* ffbuf  = Aa(2752512);
  int*   idxb   = (int*)Aa(128);
  float* sel    = Aa(49152);
  float* fo     = Aa(49152);
  float* ftmp   = Aa(49152);
  float* fxf    = Aa(49152);
  float* ffused = Aa(49152);
  float* fffb   = Aa(196608);

  // setup-phase temps inside ffbuf
  float* sc512   = ffbuf;                // 2*500*512 = 512000
  float* Cfuse3f = ffbuf + 600000;       // 1152*384 = 442368
  float* Cvkf    = ffbuf + 1100000;      // 147456
  float* Wconvf  = ffbuf + 1300000;      // 589824
  float* VT      = tmpb;                 // 2*192*512 = 196608
  // final-stage aliases
  float* seqf = pairs;
  float* go   = obuf;
  float* gtmp = obuf + 98304;
  float* gx1  = obuf + 196608;
  float* gx2  = obuf + 294912;
  float* logitsb = qkvbuf;

  float* lossBase = (float*)d_out + 128*502;

  // split-arena segment offsets (elements)
  const int o_qkvdyn=0, o_outdyn=442368, o_wconv=589824,
            o_tlin0=1179648, o_tlin1=1622016, o_tlout0=2064384, o_tlout1=2211840,
            o_tlff1_0=2359296, o_tlff1_1=2949120, o_tlff2_0=3538944, o_tlff2_1=4128768,
            o_mhaout=4718592, o_ff1=4866048, o_ff2=5455872, o_cfuse=6045696, o_cvk=6488064;
  const int split_total = 6635520;

  const float s192 = 0.07216878364870322f;  // 1/sqrt(192)

  // ---------- stage 1: relation_mem ----------
  gemm3<0><<<dim3(8,18),256,0,stream>>>(emb,384, qkv_dyn_w,384, qkvbuf,1152, qkv_dyn_b, 500,1152,384, 1.f);
  for(int h=0;h<2;h++)
    gemm3<0><<<dim3(8,8),256,0,stream>>>(qkvbuf + h*192,1152, qkvbuf + 384 + h*192,1152,
           sc512 + (size_t)h*256000,512, nullptr, 500,512,192, s192);
  softmax_rows<<<1000,256,0,stream>>>(sc512, 512, 500);
  vt_k<<<CDIV(2*192*512,256),256,0,stream>>>(qkvbuf, VT);
  for(int h=0;h<2;h++)
    gemm3<0><<<dim3(8,3),256,0,stream>>>(sc512 + (size_t)h*256000,512, VT + h*98304,512,
           obuf + h*192,384, nullptr, 500,192,512, 1.f);
  gemm3<0><<<dim3(8,6),256,0,stream>>>(obuf,384, out_dyn_w,384, xbuf,384, out_dyn_b, 500,384,384, 1.f);
  add_ln<<<500,128,0,stream>>>(emb, xbuf, relmem, ln_dyn_g, ln_dyn_b, 500);

  // ---------- compositions ----------
  gemm_nn<<<dim3(6,6),256,0,stream>>>(mha_in_w,384,            fcq_w,384, Cfuse3f,384,          384,384,384, 1.f);
  gemm_nn<<<dim3(6,6),256,0,stream>>>(mha_in_w + 384*384,384,  fck_w,384, Cfuse3f + 147456,384, 384,384,384, 1.f);
  gemm_nn<<<dim3(6,6),256,0,stream>>>(mha_in_w + 768*384,384,  fcv_w,384, Cfuse3f + 294912,384, 384,384,384, 1.f);
  gemm_nn<<<dim3(6,6),256,0,stream>>>(mha_in_w + 768*384,384,  fck_w,384, Cvkf,384,             384,384,384, 1.f);
  compose_bias<<<6,256,0,stream>>>(mha_in_w, mha_in_b, fcq_b, fck_b, fcv_b, cb);

  // ---------- batch-invariant K/V for fuse/final ----------
  gemm3<0><<<dim3(8,6),256,0,stream>>>(relmem,384, Cfuse3f + 147456,384, K1mem,384, cb+384,  500,384,384, 1.f);
  gemm3<0><<<dim3(8,6),256,0,stream>>>(relmem,384, Cfuse3f + 294912,384, V1f,384,   cb+768,  500,384,384, 1.f);
  gemm3<0><<<dim3(8,6),256,0,stream>>>(relmem,384, Cvkf,384,            V1l,384,   cb+1152, 500,384,384, 1.f);

  prep_conv<<<CDIV(384*384,256),256,0,stream>>>(conv_w, conv_b, Wconvf, cb768);

  // ---------- split all hot-loop weights ----------
  {
    SplitArgs a;
    const float* srcs[NSEG] = { qkv_dyn_w, out_dyn_w, Wconvf, tl_in_w, tl_in_w + 442368,
                                tl_out_w, tl_out_w + 147456, tl_ff1_w, tl_ff1_w + 589824,
                                tl_ff2_w, tl_ff2_w + 589824, mha_out_w, ff1_w, ff2_w,
                                Cfuse3f, Cvkf };
    const int offs[NSEG+1] = { o_qkvdyn, o_outdyn, o_wconv, o_tlin0, o_tlin1, o_tlout0, o_tlout1,
                               o_tlff1_0, o_tlff1_1, o_tlff2_0, o_tlff2_1, o_mhaout, o_ff1, o_ff2,
                               o_cfuse, o_cvk, split_total };
    for(int s=0;s<NSEG;s++){
      a.src[s]=srcs[s]; a.dh[s]=SH+offs[s]; a.dl[s]=SL+offs[s]; a.start[s]=offs[s];
    }
    a.start[NSEG]=split_total;
    split_all<<<CDIV(split_total,256),256,0,stream>>>(a);
  }
  seq_init<<<CDIV(128*8*384,256),256,0,stream>>>(inputs, emb, rel_pos, seqA_);

  float* seqCur = seqA_; float* seqNxt = seqB_;

  // ---------- merge loop ----------
  for(int it=0; it<6; ++it){
    int P = 7 - it;
    int N = 128 * P;
    build_pairs<<<CDIV(N*768,256),256,0,stream>>>(seqCur, rel_pos, pairs, N, P);
    gemm3s<0><<<dim3(N/64,12),256,0,stream>>>(pairs,768, SH+o_wconv,SL+o_wconv,768,
                                              xbuf,768, cb768, N,768,768);
    for(int l=0;l<2;l++){
      int oin  = l? o_tlin1  : o_tlin0;
      int oout = l? o_tlout1 : o_tlout0;
      int of1  = l? o_tlff1_1: o_tlff1_0;
      int of2  = l? o_tlff2_1: o_tlff2_0;
      gemm3s<0><<<dim3(2*N/64,18),256,0,stream>>>(xbuf,384, SH+oin,SL+oin,384,
                                                  qkvbuf,1152, tl_in_b + l*1152, 2*N,1152,384);
      attn2_fused<<<CDIV(2*N,8),512,0,stream>>>(qkvbuf, obuf, 2*N);
      gemm3s<0><<<dim3(2*N/64,6),256,0,stream>>>(obuf,384, SH+oout,SL+oout,384,
                                                 tmpb,384, tl_out_b + l*384, 2*N,384,384);
      add_ln<<<2*N,128,0,stream>>>(xbuf, tmpb, xbuf, tl_ln1_g + l*384, tl_ln1_b + l*384, 2*N);
      gemm3s<1><<<dim3(2*N/64,24),256,0,stream>>>(xbuf,384, SH+of1,SL+of1,384,
                                                  ffbuf,1536, tl_ff1_b + l*1536, 2*N,1536,384);
      gemm3s<0><<<dim3(2*N/64,6),256,0,stream>>>(ffbuf,1536, SH+of2,SL+of2,1536,
                                                 tmpb,384, tl_ff2_b + l*384, 2*N,384,1536);
      add_ln<<<2*N,128,0,stream>>>(xbuf, tmpb, xbuf, tl_ln2_g + l*384, tl_ln2_b + l*384, 2*N);
    }
    score_select<<<128,256,0,stream>>>(xbuf, fc_score_w, fc_score_b, P, idxb, lossBase + it, sel);
    gemm3s<0><<<dim3(2,18),256,0,stream>>>(sel,384, SH+o_cfuse,SL+o_cfuse,384,
                                           fqkv1,1152, cb, 128,1152,384);
    attn_mem<1><<<128,384,0,stream>>>(fqkv1, K1mem, V1f, fo);
    gemm3s<0><<<dim3(2,6),256,0,stream>>>(fo,384, SH+o_mhaout,SL+o_mhaout,384,
                                          ftmp,384, mha_out_b, 128,384,384);
    add_ln<<<128,128,0,stream>>>(sel, ftmp, fxf, lnf1_g, lnf1_b, 128);
    gemm3s<1><<<dim3(2,24),256,0,stream>>>(fxf,384, SH+o_ff1,SL+o_ff1,384,
                                           fffb,1536, ff1_b, 128,1536,384);
    gemm3s<0><<<dim3(2,6),256,0,stream>>>(fffb,1536, SH+o_ff2,SL+o_ff2,1536,
                                          ftmp,384, ff2_b, 128,384,1536);
    add_ln<<<128,128,0,stream>>>(fxf, ftmp, ffused, lnf2_g, lnf2_b, 128);
    merge_seq<<<CDIV(128*P*384,256),256,0,stream>>>(seqCur, ffused, idxb, seqNxt, P);
    float* t_ = seqCur; seqCur = seqNxt; seqNxt = t_;
  }
  zero_loss6<<<1,128,0,stream>>>(lossBase);

  // ---------- final stage (Lf = 2) ----------
  compact_seq<<<CDIV(256*384,256),256,0,stream>>>(seqCur, seqf);
  gemm3s<0><<<dim3(4,12),256,0,stream>>>(seqf,384, SH+o_cfuse,SL+o_cfuse,384,
                                         gqkv1,1152, cb, 256,768,384);
  gemm3s<0><<<dim3(4,6),256,0,stream>>>(seqf,384, SH+o_cvk,SL+o_cvk,384,
                                        gqkv1+768,1152, cb+1152, 256,384,384);
  attn_mem<2><<<256,384,0,stream>>>(gqkv1, K1mem, V1l, go);
  gemm3s<0><<<dim3(4,6),256,0,stream>>>(go,384, SH+o_mhaout,SL+o_mhaout,384,
                                        gtmp,384, mha_out_b, 256,384,384);
  add_ln<<<256,128,0,stream>>>(seqf, gtmp, gx1, lnf1_g, lnf1_b, 256);
  gemm3s<1><<<dim3(4,24),256,0,stream>>>(gx1,384, SH+o_ff1,SL+o_ff1,384,
                                         ffbuf,1536, ff1_b, 256,1536,384);
  gemm3s<0><<<dim3(4,6),256,0,stream>>>(ffbuf,1536, SH+o_ff2,SL+o_ff2,1536,
                                        gtmp,384, ff2_b, 256,384,1536);
  add_ln<<<256,128,0,stream>>>(gx1, gtmp, gx2, lnf2_g, lnf2_b, 256);
  logits_k<<<CDIV(256*502,256),256,0,stream>>>(gx2, relmem, seqf, logitsb);
  pred_copy<<<CDIV(128*502,256),256,0,stream>>>(logitsb, (float*)d_out);
  final_ent<<<256,256,0,stream>>>(logitsb, lossBase);
}